// Round 4
// baseline (345.641 us; speedup 1.0000x reference)
//
#include <hip/hip_runtime.h>
#include <math.h>

#define D     64
#define NSLOT 8
#define NB    64
#define NROW  4096
#define EPS   1e-5f

// ---------------------------------------------------------------------------
// helpers
// ---------------------------------------------------------------------------
__device__ __forceinline__ float wredsum(float v) {
  #pragma unroll
  for (int m = 1; m < 64; m <<= 1) v += __shfl_xor(v, m);
  return v;
}

// Coalesced wave matvec: out[r] = W[r,:] . lin  for r in [0,R), C=64.
// 16-lane group g computes row rb*4+g; lane q=lane&15 holds 4 input elems.
// W row loads are 1KiB contiguous per wave per iteration.
template <int R>
__device__ __forceinline__ void matvec_grp(const float* __restrict__ W,
                                           const float* lin, float* lout,
                                           int lane) {
  const int g = lane >> 4, q = lane & 15;
  const float4 iv = *reinterpret_cast<const float4*>(lin + 4 * q);
  #pragma unroll
  for (int rb = 0; rb < (R >> 2); ++rb) {
    const int r = rb * 4 + g;
    const float4 w = *reinterpret_cast<const float4*>(W + r * 64 + 4 * q);
    float p = w.x * iv.x + w.y * iv.y + w.z * iv.z + w.w * iv.w;
    p += __shfl_xor(p, 1);
    p += __shfl_xor(p, 2);
    p += __shfl_xor(p, 4);
    p += __shfl_xor(p, 8);
    if (q == 0) lout[r] = p;
  }
}

// Same but C=128 (for W2: out 64, in 128).
template <int R>
__device__ __forceinline__ void matvec_grp_c128(const float* __restrict__ W,
                                                const float* lin, float* lout,
                                                int lane) {
  const int g = lane >> 4, q = lane & 15;
  const float4 iv0 = *reinterpret_cast<const float4*>(lin + 4 * q);
  const float4 iv1 = *reinterpret_cast<const float4*>(lin + 64 + 4 * q);
  #pragma unroll
  for (int rb = 0; rb < (R >> 2); ++rb) {
    const int r = rb * 4 + g;
    const float4 w0 = *reinterpret_cast<const float4*>(W + r * 128 + 4 * q);
    const float4 w1 = *reinterpret_cast<const float4*>(W + r * 128 + 64 + 4 * q);
    float p = w0.x * iv0.x + w0.y * iv0.y + w0.z * iv0.z + w0.w * iv0.w
            + w1.x * iv1.x + w1.y * iv1.y + w1.z * iv1.z + w1.w * iv1.w;
    p += __shfl_xor(p, 1);
    p += __shfl_xor(p, 2);
    p += __shfl_xor(p, 4);
    p += __shfl_xor(p, 8);
    if (q == 0) lout[r] = p;
  }
}

// ---------------------------------------------------------------------------
// KA: the big per-iteration pass over x (unchanged from r2 — ~19us, near
// VALU/BW balance; tune next once its counters are visible).
// ---------------------------------------------------------------------------
__global__ __launch_bounds__(256, 2)
void ka_kernel(const float* __restrict__ x,
               const float* __restrict__ qtil,
               const float* __restrict__ cvec,
               float* __restrict__ U, float* __restrict__ S) {
  const int b    = blockIdx.x >> 4;   // 16 row-blocks per batch
  const int rb   = blockIdx.x & 15;
  const int tid  = threadIdx.x;
  const int wave = tid >> 6;
  const int lane = tid & 63;
  const int c    = lane & 15;         // d-chunk index (4 floats)

  const float4* qt4 = reinterpret_cast<const float4*>(qtil + (size_t)b * NSLOT * D);
  float4 qf[NSLOT];
  float  cs[NSLOT];
  #pragma unroll
  for (int s = 0; s < NSLOT; ++s) {
    qf[s] = qt4[s * 16 + c];
    cs[s] = cvec[b * NSLOT + s];
  }

  float4 Ua[NSLOT];
  float  Sa[NSLOT];
  #pragma unroll
  for (int s = 0; s < NSLOT; ++s) { Ua[s] = make_float4(0.f, 0.f, 0.f, 0.f); Sa[s] = 0.f; }

  const float4* xb = reinterpret_cast<const float4*>(
      x + ((size_t)b * NROW + rb * 256 + wave * 64) * D);

  #pragma unroll 2
  for (int it = 0; it < 16; ++it) {
    float4 xv = xb[it * 64 + lane];  // 4 rows x 64 floats, fully coalesced

    // --- LayerNorm over the 16-lane group (row) ---
    float s1 = xv.x + xv.y + xv.z + xv.w;
    float s2 = xv.x * xv.x + xv.y * xv.y + xv.z * xv.z + xv.w * xv.w;
    #pragma unroll
    for (int m = 1; m < 16; m <<= 1) {
      s1 += __shfl_xor(s1, m);
      s2 += __shfl_xor(s2, m);
    }
    float mean = s1 * (1.f / 64.f);
    float var  = s2 * (1.f / 64.f) - mean * mean;
    float rstd = rsqrtf(var + EPS);
    float nb   = -mean * rstd;
    float4 xn;
    xn.x = fmaf(xv.x, rstd, nb);
    xn.y = fmaf(xv.y, rstd, nb);
    xn.z = fmaf(xv.z, rstd, nb);
    xn.w = fmaf(xv.w, rstd, nb);

    // --- logits ---
    float p[NSLOT];
    #pragma unroll
    for (int s = 0; s < NSLOT; ++s)
      p[s] = xn.x * qf[s].x + xn.y * qf[s].y + xn.z * qf[s].z + xn.w * qf[s].w;
    #pragma unroll
    for (int m = 1; m < 16; m <<= 1) {
      #pragma unroll
      for (int s = 0; s < NSLOT; ++s) p[s] += __shfl_xor(p[s], m);
    }
    #pragma unroll
    for (int s = 0; s < NSLOT; ++s) p[s] += cs[s];

    // --- softmax over 8 slots ---
    float mx = fmaxf(fmaxf(fmaxf(p[0], p[1]), fmaxf(p[2], p[3])),
                     fmaxf(fmaxf(p[4], p[5]), fmaxf(p[6], p[7])));
    float sum = 0.f;
    #pragma unroll
    for (int s = 0; s < NSLOT; ++s) {
      p[s] = exp2f((p[s] - mx) * 1.44269504f);
      sum += p[s];
    }
    float inv = 1.f / sum;
    #pragma unroll
    for (int s = 0; s < NSLOT; ++s) {
      float a = p[s] * inv + 1e-8f;
      Sa[s] += a;
      Ua[s].x = fmaf(a, xn.x, Ua[s].x);
      Ua[s].y = fmaf(a, xn.y, Ua[s].y);
      Ua[s].z = fmaf(a, xn.z, Ua[s].z);
      Ua[s].w = fmaf(a, xn.w, Ua[s].w);
    }
  }

  // cross-group reduce within wave
  #pragma unroll
  for (int m = 16; m < 64; m <<= 1) {
    #pragma unroll
    for (int s = 0; s < NSLOT; ++s) {
      Sa[s]   += __shfl_xor(Sa[s], m);
      Ua[s].x += __shfl_xor(Ua[s].x, m);
      Ua[s].y += __shfl_xor(Ua[s].y, m);
      Ua[s].z += __shfl_xor(Ua[s].z, m);
      Ua[s].w += __shfl_xor(Ua[s].w, m);
    }
  }

  __shared__ float lU[4][NSLOT][D];
  __shared__ float lS[4][NSLOT];
  if (lane < 16) {
    #pragma unroll
    for (int s = 0; s < NSLOT; ++s) {
      lU[wave][s][4 * c + 0] = Ua[s].x;
      lU[wave][s][4 * c + 1] = Ua[s].y;
      lU[wave][s][4 * c + 2] = Ua[s].z;
      lU[wave][s][4 * c + 3] = Ua[s].w;
    }
    if (c == 0) {
      #pragma unroll
      for (int s = 0; s < NSLOT; ++s) lS[wave][s] = Sa[s];
    }
  }
  __syncthreads();

  for (int cell = tid; cell < NSLOT * D; cell += 256) {
    int s = cell >> 6, d = cell & 63;
    atomicAdd(&U[((size_t)b * NSLOT + s) * D + d],
              lU[0][s][d] + lU[1][s][d] + lU[2][s][d] + lU[3][s][d]);
  }
  if (tid < NSLOT) {
    atomicAdd(&S[b * NSLOT + tid],
              lS[0][tid] + lS[1][tid] + lS[2][tid] + lS[3][tid]);
  }
}

// ---------------------------------------------------------------------------
// KB: per-(batch,slot) slot update. 512 blocks x 64 threads (1 wave).
// All matvecs use the coalesced 16-lane-group pattern (1KiB/wave/instr);
// weight rows are never read with per-lane row scatter. Single-wave LDS
// comms, no barriers needed.
// ---------------------------------------------------------------------------
__global__ __launch_bounds__(64)
void kb_kernel(int mode, int last,
               const float* __restrict__ noise, const float* __restrict__ mu,
               const float* __restrict__ sigma,
               const float* __restrict__ Wq, const float* __restrict__ bq,
               const float* __restrict__ Wk, const float* __restrict__ bk,
               const float* __restrict__ Wv, const float* __restrict__ bv,
               const float* __restrict__ Wih, const float* __restrict__ Whh,
               const float* __restrict__ bih, const float* __restrict__ bhh,
               const float* __restrict__ W1, const float* __restrict__ b1,
               const float* __restrict__ W2, const float* __restrict__ b2,
               float* __restrict__ slots, float* __restrict__ qtil,
               float* __restrict__ cvec, float* __restrict__ U,
               float* __restrict__ S, float* __restrict__ out) {
  const int blk = blockIdx.x;
  const int b   = blk >> 3;
  const int s   = blk & 7;
  const int d   = threadIdx.x;      // lane 0..63
  const int idx = (b * NSLOT + s) * D + d;

  __shared__ float bufA[64];    // matvec input
  __shared__ float bufB[192];   // gi (192) / generic out
  __shared__ float bufC[192];   // gh (192)
  __shared__ float bufH[128];   // mlp hidden

  float h;
  if (mode == 0) {
    h = mu[d] + sigma[d] * noise[idx];
    U[idx] = 0.f;
    if (d == 0) S[b * NSLOT + s] = 0.f;
    slots[idx] = h;
  } else {
    float Uv = U[idx];
    float Ss = S[b * NSLOT + s];
    U[idx] = 0.f;
    if (d == 0) S[b * NSLOT + s] = 0.f;

    // updates = Wv @ (U/S) + bv
    bufA[d] = Uv / Ss;
    matvec_grp<64>(Wv, bufA, bufB, d);
    float upd = bufB[d] + bv[d];
    bufA[d] = upd;                      // bufA re-written after matvec consumed it

    // GRU
    h = slots[idx];
    bufH[d] = h;
    matvec_grp<192>(Wih, bufA, bufB, d);   // gi
    matvec_grp<192>(Whh, bufH, bufC, d);   // gh
    float r  = 1.f / (1.f + expf(-(bufB[d]       + bih[d]       + bufC[d]       + bhh[d])));
    float z  = 1.f / (1.f + expf(-(bufB[64 + d]  + bih[64 + d]  + bufC[64 + d]  + bhh[64 + d])));
    float nn = tanhf(bufB[128 + d] + bih[128 + d] + r * (bufC[128 + d] + bhh[128 + d]));
    h = (1.f - z) * nn + z * h;

    // LayerNorm
    float m  = wredsum(h) * (1.f / 64.f);
    float hc = h - m;
    float v  = wredsum(hc * hc) * (1.f / 64.f);
    float sl = hc * rsqrtf(v + EPS);

    // MLP with residual
    bufA[d] = sl;
    matvec_grp<128>(W1, bufA, bufB, d);
    bufH[d]      = fmaxf(bufB[d]      + b1[d],      0.f);
    bufH[64 + d] = fmaxf(bufB[64 + d] + b1[64 + d], 0.f);
    matvec_grp_c128<64>(W2, bufH, bufC, d);
    h = sl + bufC[d] + b2[d];
    slots[idx] = h;
    if (last) out[idx] = h;
  }

  if (!last) {
    // q = LN(slots) @ Wq^T + bq ; q~ = scale*(q @ Wk) ; c = scale*(bk.q)
    float m  = wredsum(h) * (1.f / 64.f);
    float hc = h - m;
    float v  = wredsum(hc * hc) * (1.f / 64.f);
    float ln = hc * rsqrtf(v + EPS);

    bufA[d] = ln;
    matvec_grp<64>(Wq, bufA, bufB, d);
    float qv = bufB[d] + bq[d];
    bufC[d] = qv;

    // qt[d] = sum_e q[e] * Wk[e*64+d]  — Wk access already coalesced along d
    float qt0 = 0.f, qt1 = 0.f, qt2 = 0.f, qt3 = 0.f;
    #pragma unroll
    for (int e = 0; e < 64; e += 4) {
      const float4 qb = *reinterpret_cast<const float4*>(bufC + e);  // uniform addr → broadcast
      qt0 = fmaf(Wk[(e + 0) * D + d], qb.x, qt0);
      qt1 = fmaf(Wk[(e + 1) * D + d], qb.y, qt1);
      qt2 = fmaf(Wk[(e + 2) * D + d], qb.z, qt2);
      qt3 = fmaf(Wk[(e + 3) * D + d], qb.w, qt3);
    }
    const float sc = 0.125f;  // 1/sqrt(64)
    qtil[idx] = ((qt0 + qt1) + (qt2 + qt3)) * sc;
    float ca = wredsum(bk[d] * qv) * sc;
    if (d == 0) cvec[b * NSLOT + s] = ca;
  }
}

// ---------------------------------------------------------------------------
extern "C" void kernel_launch(void* const* d_in, const int* in_sizes, int n_in,
                              void* d_out, int out_size, void* d_ws, size_t ws_size,
                              hipStream_t stream) {
  (void)in_sizes; (void)n_in; (void)out_size; (void)ws_size;
  const float* x     = (const float*)d_in[0];
  const float* noise = (const float*)d_in[1];
  const float* Wq    = (const float*)d_in[2];
  const float* bq    = (const float*)d_in[3];
  const float* Wk    = (const float*)d_in[4];
  const float* bk    = (const float*)d_in[5];
  const float* Wv    = (const float*)d_in[6];
  const float* bv    = (const float*)d_in[7];
  const float* Wih   = (const float*)d_in[8];
  const float* Whh   = (const float*)d_in[9];
  const float* bih   = (const float*)d_in[10];
  const float* bhh   = (const float*)d_in[11];
  const float* W1    = (const float*)d_in[12];
  const float* b1    = (const float*)d_in[13];
  const float* W2    = (const float*)d_in[14];
  const float* b2    = (const float*)d_in[15];
  const float* mu    = (const float*)d_in[16];
  const float* sigma = (const float*)d_in[17];

  float* ws    = (float*)d_ws;
  float* slots = ws;          // 64*8*64 = 32768
  float* qtil  = ws + 32768;  // 32768
  float* cvec  = ws + 65536;  // 512
  float* U     = ws + 66048;  // 32768
  float* S     = ws + 98816;  // 512
  float* out   = (float*)d_out;

  auto launch_kb = [&](int mode, int last) {
    kb_kernel<<<NB * NSLOT, 64, 0, stream>>>(mode, last, noise, mu, sigma,
                                             Wq, bq, Wk, bk, Wv, bv,
                                             Wih, Whh, bih, bhh, W1, b1, W2, b2,
                                             slots, qtil, cvec, U, S, out);
  };

  launch_kb(0, 0);  // init slots, q~, zero U/S
  for (int it = 1; it <= 3; ++it) {
    ka_kernel<<<NB * 16, 256, 0, stream>>>(x, qtil, cvec, U, S);
    launch_kb(1, it == 3 ? 1 : 0);
  }
}

// Round 5
// 234.669 us; speedup vs baseline: 1.4729x; 1.4729x over previous
//
#include <hip/hip_runtime.h>
#include <math.h>

#define D     64
#define NSLOT 8
#define NB    64
#define NROW  4096
#define EPS   1e-5f

// ---------------------------------------------------------------------------
// helpers
// ---------------------------------------------------------------------------
__device__ __forceinline__ float wredsum(float v) {
  #pragma unroll
  for (int m = 1; m < 64; m <<= 1) v += __shfl_xor(v, m);
  return v;
}

// Coalesced wave matvec with FULL register preload of the weight panel.
// out[r] = W[r,:] . lin  for r in [0,R), C=64. 16-lane group g computes
// row rb*4+g; lane q=lane&15 holds 4 input elems. All R/4 float4 weight
// loads are issued before any consumption -> one vmcnt batch (needs
// __launch_bounds__(64,1) for the VGPR budget; indices compile-time).
template <int R>
__device__ __forceinline__ void matvec_pre(const float* __restrict__ W,
                                           const float* lin, float* lout,
                                           int lane) {
  const int g = lane >> 4, q = lane & 15;
  float4 w[R >> 2];
  #pragma unroll
  for (int rb = 0; rb < (R >> 2); ++rb)
    w[rb] = *reinterpret_cast<const float4*>(W + (rb * 4 + g) * 64 + 4 * q);
  const float4 iv = *reinterpret_cast<const float4*>(lin + 4 * q);
  #pragma unroll
  for (int rb = 0; rb < (R >> 2); ++rb) {
    float p = w[rb].x * iv.x + w[rb].y * iv.y + w[rb].z * iv.z + w[rb].w * iv.w;
    p += __shfl_xor(p, 1);
    p += __shfl_xor(p, 2);
    p += __shfl_xor(p, 4);
    p += __shfl_xor(p, 8);
    if (q == 0) lout[rb * 4 + g] = p;
  }
}

// Same, C=128 (for W2: out 64, in 128).
__device__ __forceinline__ void matvec_pre_c128(const float* __restrict__ W,
                                                const float* lin, float* lout,
                                                int lane) {
  const int g = lane >> 4, q = lane & 15;
  float4 w0[16], w1[16];
  #pragma unroll
  for (int rb = 0; rb < 16; ++rb) {
    w0[rb] = *reinterpret_cast<const float4*>(W + (rb * 4 + g) * 128 + 4 * q);
    w1[rb] = *reinterpret_cast<const float4*>(W + (rb * 4 + g) * 128 + 64 + 4 * q);
  }
  const float4 iv0 = *reinterpret_cast<const float4*>(lin + 4 * q);
  const float4 iv1 = *reinterpret_cast<const float4*>(lin + 64 + 4 * q);
  #pragma unroll
  for (int rb = 0; rb < 16; ++rb) {
    float p = w0[rb].x * iv0.x + w0[rb].y * iv0.y + w0[rb].z * iv0.z + w0[rb].w * iv0.w
            + w1[rb].x * iv1.x + w1[rb].y * iv1.y + w1[rb].z * iv1.z + w1[rb].w * iv1.w;
    p += __shfl_xor(p, 1);
    p += __shfl_xor(p, 2);
    p += __shfl_xor(p, 4);
    p += __shfl_xor(p, 8);
    if (q == 0) lout[rb * 4 + g] = p;
  }
}

// ---------------------------------------------------------------------------
// KPREP: one-time weight folding (runs once per launch, 4 blocks).
//   block 0: Mt[d][e] = sum_f Wq[f][e]*Wk[f][d]   (so qt = Mt @ ln)
//            ct[d]    = sum_f bq[f]*Wk[f][d]
//            u[e]     = sum_f bk[f]*Wq[f][e]
//            c0       = bk . bq
//   blocks 1-3: G = Wih @ Wv  (192x64), bias_i = Wih @ bv + bih
// ---------------------------------------------------------------------------
__global__ __launch_bounds__(256)
void kprep_kernel(const float* __restrict__ Wq, const float* __restrict__ bq,
                  const float* __restrict__ Wk, const float* __restrict__ bk,
                  const float* __restrict__ Wv, const float* __restrict__ bv,
                  const float* __restrict__ Wih, const float* __restrict__ bih,
                  float* __restrict__ Mt, float* __restrict__ ct,
                  float* __restrict__ u, float* __restrict__ c0,
                  float* __restrict__ G, float* __restrict__ bias_i) {
  const int t = threadIdx.x;
  if (blockIdx.x == 0) {
    const int dd = t >> 2;            // output row d (Mt is [d][e])
    const int e0 = (t & 3) * 16;      // 16 e's per thread
    float acc[16];
    #pragma unroll
    for (int j = 0; j < 16; ++j) acc[j] = 0.f;
    #pragma unroll 4
    for (int f = 0; f < 64; ++f) {
      float wkf = Wk[f * 64 + dd];
      const float4* wq4 = reinterpret_cast<const float4*>(Wq + f * 64 + e0);
      #pragma unroll
      for (int j4 = 0; j4 < 4; ++j4) {
        float4 wq = wq4[j4];
        acc[4 * j4 + 0] = fmaf(wkf, wq.x, acc[4 * j4 + 0]);
        acc[4 * j4 + 1] = fmaf(wkf, wq.y, acc[4 * j4 + 1]);
        acc[4 * j4 + 2] = fmaf(wkf, wq.z, acc[4 * j4 + 2]);
        acc[4 * j4 + 3] = fmaf(wkf, wq.w, acc[4 * j4 + 3]);
      }
    }
    #pragma unroll
    for (int j = 0; j < 16; ++j) Mt[dd * 64 + e0 + j] = acc[j];
    if (t < 64) {
      float a = 0.f, bsum = 0.f;
      #pragma unroll 4
      for (int f = 0; f < 64; ++f) {
        a    = fmaf(bq[f], Wk[f * 64 + t], a);
        bsum = fmaf(bk[f], Wq[f * 64 + t], bsum);
      }
      ct[t] = a;
      u[t]  = bsum;
    }
    if (t == 0) {
      float a = 0.f;
      for (int f = 0; f < 64; ++f) a = fmaf(bk[f], bq[f], a);
      c0[0] = a;
    }
  } else {
    const int r0  = (blockIdx.x - 1) * 64;
    const int r   = r0 + (t >> 2);
    const int cc0 = (t & 3) * 16;
    float acc[16];
    #pragma unroll
    for (int j = 0; j < 16; ++j) acc[j] = 0.f;
    #pragma unroll 4
    for (int f = 0; f < 64; ++f) {
      float wih = Wih[r * 64 + f];
      const float4* wv4 = reinterpret_cast<const float4*>(Wv + f * 64 + cc0);
      #pragma unroll
      for (int j4 = 0; j4 < 4; ++j4) {
        float4 wv = wv4[j4];
        acc[4 * j4 + 0] = fmaf(wih, wv.x, acc[4 * j4 + 0]);
        acc[4 * j4 + 1] = fmaf(wih, wv.y, acc[4 * j4 + 1]);
        acc[4 * j4 + 2] = fmaf(wih, wv.z, acc[4 * j4 + 2]);
        acc[4 * j4 + 3] = fmaf(wih, wv.w, acc[4 * j4 + 3]);
      }
    }
    #pragma unroll
    for (int j = 0; j < 16; ++j) G[r * 64 + cc0 + j] = acc[j];
    if (t < 64) {
      int rr = r0 + t;
      float a = bih[rr];
      #pragma unroll 4
      for (int f = 0; f < 64; ++f) a = fmaf(Wih[rr * 64 + f], bv[f], a);
      bias_i[rr] = a;
    }
  }
}

// ---------------------------------------------------------------------------
// KA: the big per-iteration pass over x (unchanged; ~19us each).
// ---------------------------------------------------------------------------
__global__ __launch_bounds__(256, 2)
void ka_kernel(const float* __restrict__ x,
               const float* __restrict__ qtil,
               const float* __restrict__ cvec,
               float* __restrict__ U, float* __restrict__ S) {
  const int b    = blockIdx.x >> 4;   // 16 row-blocks per batch
  const int rb   = blockIdx.x & 15;
  const int tid  = threadIdx.x;
  const int wave = tid >> 6;
  const int lane = tid & 63;
  const int c    = lane & 15;         // d-chunk index (4 floats)

  const float4* qt4 = reinterpret_cast<const float4*>(qtil + (size_t)b * NSLOT * D);
  float4 qf[NSLOT];
  float  cs[NSLOT];
  #pragma unroll
  for (int s = 0; s < NSLOT; ++s) {
    qf[s] = qt4[s * 16 + c];
    cs[s] = cvec[b * NSLOT + s];
  }

  float4 Ua[NSLOT];
  float  Sa[NSLOT];
  #pragma unroll
  for (int s = 0; s < NSLOT; ++s) { Ua[s] = make_float4(0.f, 0.f, 0.f, 0.f); Sa[s] = 0.f; }

  const float4* xb = reinterpret_cast<const float4*>(
      x + ((size_t)b * NROW + rb * 256 + wave * 64) * D);

  #pragma unroll 2
  for (int it = 0; it < 16; ++it) {
    float4 xv = xb[it * 64 + lane];  // 4 rows x 64 floats, fully coalesced

    // --- LayerNorm over the 16-lane group (row) ---
    float s1 = xv.x + xv.y + xv.z + xv.w;
    float s2 = xv.x * xv.x + xv.y * xv.y + xv.z * xv.z + xv.w * xv.w;
    #pragma unroll
    for (int m = 1; m < 16; m <<= 1) {
      s1 += __shfl_xor(s1, m);
      s2 += __shfl_xor(s2, m);
    }
    float mean = s1 * (1.f / 64.f);
    float var  = s2 * (1.f / 64.f) - mean * mean;
    float rstd = rsqrtf(var + EPS);
    float nb   = -mean * rstd;
    float4 xn;
    xn.x = fmaf(xv.x, rstd, nb);
    xn.y = fmaf(xv.y, rstd, nb);
    xn.z = fmaf(xv.z, rstd, nb);
    xn.w = fmaf(xv.w, rstd, nb);

    // --- logits ---
    float p[NSLOT];
    #pragma unroll
    for (int s = 0; s < NSLOT; ++s)
      p[s] = xn.x * qf[s].x + xn.y * qf[s].y + xn.z * qf[s].z + xn.w * qf[s].w;
    #pragma unroll
    for (int m = 1; m < 16; m <<= 1) {
      #pragma unroll
      for (int s = 0; s < NSLOT; ++s) p[s] += __shfl_xor(p[s], m);
    }
    #pragma unroll
    for (int s = 0; s < NSLOT; ++s) p[s] += cs[s];

    // --- softmax over 8 slots ---
    float mx = fmaxf(fmaxf(fmaxf(p[0], p[1]), fmaxf(p[2], p[3])),
                     fmaxf(fmaxf(p[4], p[5]), fmaxf(p[6], p[7])));
    float sum = 0.f;
    #pragma unroll
    for (int s = 0; s < NSLOT; ++s) {
      p[s] = exp2f((p[s] - mx) * 1.44269504f);
      sum += p[s];
    }
    float inv = 1.f / sum;
    #pragma unroll
    for (int s = 0; s < NSLOT; ++s) {
      float a = p[s] * inv + 1e-8f;
      Sa[s] += a;
      Ua[s].x = fmaf(a, xn.x, Ua[s].x);
      Ua[s].y = fmaf(a, xn.y, Ua[s].y);
      Ua[s].z = fmaf(a, xn.z, Ua[s].z);
      Ua[s].w = fmaf(a, xn.w, Ua[s].w);
    }
  }

  // cross-group reduce within wave
  #pragma unroll
  for (int m = 16; m < 64; m <<= 1) {
    #pragma unroll
    for (int s = 0; s < NSLOT; ++s) {
      Sa[s]   += __shfl_xor(Sa[s], m);
      Ua[s].x += __shfl_xor(Ua[s].x, m);
      Ua[s].y += __shfl_xor(Ua[s].y, m);
      Ua[s].z += __shfl_xor(Ua[s].z, m);
      Ua[s].w += __shfl_xor(Ua[s].w, m);
    }
  }

  __shared__ float lU[4][NSLOT][D];
  __shared__ float lS[4][NSLOT];
  if (lane < 16) {
    #pragma unroll
    for (int s = 0; s < NSLOT; ++s) {
      lU[wave][s][4 * c + 0] = Ua[s].x;
      lU[wave][s][4 * c + 1] = Ua[s].y;
      lU[wave][s][4 * c + 2] = Ua[s].z;
      lU[wave][s][4 * c + 3] = Ua[s].w;
    }
    if (c == 0) {
      #pragma unroll
      for (int s = 0; s < NSLOT; ++s) lS[wave][s] = Sa[s];
    }
  }
  __syncthreads();

  for (int cell = tid; cell < NSLOT * D; cell += 256) {
    int s = cell >> 6, d = cell & 63;
    atomicAdd(&U[((size_t)b * NSLOT + s) * D + d],
              lU[0][s][d] + lU[1][s][d] + lU[2][s][d] + lU[3][s][d]);
  }
  if (tid < NSLOT) {
    atomicAdd(&S[b * NSLOT + tid],
              lS[0][tid] + lS[1][tid] + lS[2][tid] + lS[3][tid]);
  }
}

// ---------------------------------------------------------------------------
// KB: per-(batch,slot) slot update. 512 blocks x 1 wave.
// Serial chain (5 weight stages after folding):
//   ub -> gi = G@ub + bias_i  (Wv folded in)
//   gh = Whh@h + bhh ; GRU ; LN
//   a = relu(W1@sl + b1) ; o = W2@a + b2 ; LN
//   qt = Mt@ln + ct ; c = u.ln + c0     (Wq,Wk folded in)
// Each stage's full weight panel preloaded to VGPRs (launch_bounds(64,1)).
// ---------------------------------------------------------------------------
__global__ __launch_bounds__(64, 1)
void kb_kernel(int mode, int last,
               const float* __restrict__ noise, const float* __restrict__ mu,
               const float* __restrict__ sigma,
               const float* __restrict__ G, const float* __restrict__ bias_i,
               const float* __restrict__ Whh, const float* __restrict__ bhh,
               const float* __restrict__ W1, const float* __restrict__ b1,
               const float* __restrict__ W2, const float* __restrict__ b2,
               const float* __restrict__ Mt, const float* __restrict__ ct,
               const float* __restrict__ u, const float* __restrict__ c0,
               float* __restrict__ slots, float* __restrict__ qtil,
               float* __restrict__ cvec, float* __restrict__ U,
               float* __restrict__ S, float* __restrict__ out) {
  const int blk = blockIdx.x;
  const int b   = blk >> 3;
  const int s   = blk & 7;
  const int d   = threadIdx.x;      // lane 0..63
  const int idx = (b * NSLOT + s) * D + d;

  __shared__ float bufA[64];    // matvec input
  __shared__ float bufB[192];   // gi / generic out
  __shared__ float bufC[192];   // gh / mlp out
  __shared__ float bufH[128];   // h, then mlp hidden

  float h;
  if (mode == 0) {
    h = mu[d] + sigma[d] * noise[idx];
    U[idx] = 0.f;
    if (d == 0) S[b * NSLOT + s] = 0.f;
    slots[idx] = h;
  } else {
    float Uv = U[idx];
    float Ss = S[b * NSLOT + s];
    U[idx] = 0.f;
    if (d == 0) S[b * NSLOT + s] = 0.f;

    // gi = G @ (U/S) + bias_i   (Wv fold)
    bufA[d] = Uv / Ss;
    h = slots[idx];
    bufH[d] = h;
    matvec_pre<192>(G, bufA, bufB, d);
    // gh = Whh @ h + bhh
    matvec_pre<192>(Whh, bufH, bufC, d);

    float r  = 1.f / (1.f + expf(-(bufB[d]       + bias_i[d]       + bufC[d]       + bhh[d])));
    float z  = 1.f / (1.f + expf(-(bufB[64 + d]  + bias_i[64 + d]  + bufC[64 + d]  + bhh[64 + d])));
    float nn = tanhf(bufB[128 + d] + bias_i[128 + d] + r * (bufC[128 + d] + bhh[128 + d]));
    h = (1.f - z) * nn + z * h;

    // LayerNorm
    float m  = wredsum(h) * (1.f / 64.f);
    float hc = h - m;
    float v  = wredsum(hc * hc) * (1.f / 64.f);
    float sl = hc * rsqrtf(v + EPS);

    // MLP with residual
    bufA[d] = sl;
    matvec_pre<128>(W1, bufA, bufB, d);
    bufH[d]      = fmaxf(bufB[d]      + b1[d],      0.f);
    bufH[64 + d] = fmaxf(bufB[64 + d] + b1[64 + d], 0.f);
    matvec_pre_c128(W2, bufH, bufC, d);
    h = sl + bufC[d] + b2[d];
    slots[idx] = h;
    if (last) out[idx] = h;
  }

  if (!last) {
    // ln = LN(slots); qtil = scale*(Mt@ln + ct); c = scale*(u.ln + c0)
    float m  = wredsum(h) * (1.f / 64.f);
    float hc = h - m;
    float v  = wredsum(hc * hc) * (1.f / 64.f);
    float ln = hc * rsqrtf(v + EPS);

    bufA[d] = ln;
    matvec_pre<64>(Mt, bufA, bufB, d);
    const float sc = 0.125f;  // 1/sqrt(64)
    qtil[idx] = sc * (bufB[d] + ct[d]);
    float ca = (wredsum(u[d] * ln) + c0[0]) * sc;
    if (d == 0) cvec[b * NSLOT + s] = ca;
  }
}

// ---------------------------------------------------------------------------
extern "C" void kernel_launch(void* const* d_in, const int* in_sizes, int n_in,
                              void* d_out, int out_size, void* d_ws, size_t ws_size,
                              hipStream_t stream) {
  (void)in_sizes; (void)n_in; (void)out_size; (void)ws_size;
  const float* x     = (const float*)d_in[0];
  const float* noise = (const float*)d_in[1];
  const float* Wq    = (const float*)d_in[2];
  const float* bq    = (const float*)d_in[3];
  const float* Wk    = (const float*)d_in[4];
  const float* bk    = (const float*)d_in[5];
  const float* Wv    = (const float*)d_in[6];
  const float* bv    = (const float*)d_in[7];
  const float* Wih   = (const float*)d_in[8];
  const float* Whh   = (const float*)d_in[9];
  const float* bih   = (const float*)d_in[10];
  const float* bhh   = (const float*)d_in[11];
  const float* W1    = (const float*)d_in[12];
  const float* b1    = (const float*)d_in[13];
  const float* W2    = (const float*)d_in[14];
  const float* b2    = (const float*)d_in[15];
  const float* mu    = (const float*)d_in[16];
  const float* sigma = (const float*)d_in[17];

  float* ws     = (float*)d_ws;
  float* slots  = ws;           // 32768
  float* qtil   = ws + 32768;   // 32768
  float* cvec   = ws + 65536;   // 512
  float* U      = ws + 66048;   // 32768
  float* S      = ws + 98816;   // 512
  float* Mt     = ws + 99328;   // 4096
  float* ct     = ws + 103424;  // 64
  float* uvec   = ws + 103488;  // 64
  float* c0     = ws + 103552;  // 4 (padded)
  float* G      = ws + 103556;  // 12288
  float* bias_i = ws + 115844;  // 192  (ends 116036 floats = 464KB)
  float* out    = (float*)d_out;

  kprep_kernel<<<4, 256, 0, stream>>>(Wq, bq, Wk, bk, Wv, bv, Wih, bih,
                                      Mt, ct, uvec, c0, G, bias_i);

  auto launch_kb = [&](int mode, int last) {
    kb_kernel<<<NB * NSLOT, 64, 0, stream>>>(mode, last, noise, mu, sigma,
                                             G, bias_i, Whh, bhh, W1, b1, W2, b2,
                                             Mt, ct, uvec, c0,
                                             slots, qtil, cvec, U, S, out);
  };

  launch_kb(0, 0);  // init slots, q~, zero U/S
  for (int it = 1; it <= 3; ++it) {
    ka_kernel<<<NB * 16, 256, 0, stream>>>(x, qtil, cvec, U, S);
    launch_kb(1, it == 3 ? 1 : 0);
  }
}